// Round 8
// baseline (250.491 us; speedup 1.0000x reference)
//
#include <hip/hip_runtime.h>
#include <hip/hip_bf16.h>
#include <hip/hip_cooperative_groups.h>

namespace cg = cooperative_groups;

#define BLOCK 256
#define GRID  1024
#define WAVES_PER_BLOCK (BLOCK / 64)
#define EPT   4                      // edges per thread (preloaded batch)
#define CAP   (GRID * BLOCK * EPT)   // 1,048,576 edges covered by preload

typedef int   vint4   __attribute__((ext_vector_type(4)));
typedef float vfloat4 __attribute__((ext_vector_type(4)));

__device__ __forceinline__ float softplus(float x) {
    return fmaxf(x, 0.0f) + log1pf(expf(-fabsf(x)));
}

// Single cooperative kernel.
// Phase A: issue per-thread edge/label stream loads (registers, nontemporal,
//          in flight under proj), then per-node logit-difference projections:
//            dS[n] = z_n . (W[0:128,1]   - W[0:128,0])
//            dD[n] = z_n . (W[128:256,1] - W[128:256,0])
//          (2-class identity: loss = softplus(s_wrong - s_correct),
//           s1 - s0 = dS[src] + dD[dst].)
// grid.sync()
// Phase B: 2 gathers/edge from the 400KB L2-resident tables + softplus,
//          block reduce -> partials.
// grid.sync()
// Block 0: deterministic fixed-order final reduce -> out[0].
__global__ void __launch_bounds__(BLOCK) fused_kernel(
    const float* __restrict__ Z,
    const float* __restrict__ W,
    const int*   __restrict__ edges,
    const int*   __restrict__ y,
    float*       __restrict__ dS,
    float*       __restrict__ dD,
    float*       __restrict__ partials,
    float*       __restrict__ out,
    int n_nodes, int n_edges, float inv_m)
{
    const int tid  = blockIdx.x * BLOCK + threadIdx.x;
    const int base = tid * EPT;

    // ---- issue edge/label stream loads early; results used only in phase B.
    vint4 e01 = {0, 0, 0, 0}, e23 = {0, 0, 0, 0}, yy = {0, 0, 0, 0};
    const bool full = (base + EPT - 1 < n_edges);
    if (full) {
        e01 = __builtin_nontemporal_load(((const vint4*)edges) + 2 * tid);
        e23 = __builtin_nontemporal_load(((const vint4*)edges) + 2 * tid + 1);
        yy  = __builtin_nontemporal_load(((const vint4*)y) + tid);
    }

    // ---- Phase A: projection (half-wave: lanes 0..31 node 2p, 32..63 node 2p+1)
    {
        const int lane = threadIdx.x & 63;
        const int wid  = threadIdx.x >> 6;
        const int sub  = lane & 31;   // float4 index within the 128-float row
        const int half = lane >> 5;   // which node of the pair
        const int gw   = blockIdx.x * WAVES_PER_BLOCK + wid;
        const int nwaves = GRID * WAVES_PER_BLOCK;

        const int k0 = 4 * sub;
        float wds[4], wdd[4];
#pragma unroll
        for (int j = 0; j < 4; ++j) {
            wds[j] = W[(k0 + j) * 2 + 1]       - W[(k0 + j) * 2 + 0];
            wdd[j] = W[(128 + k0 + j) * 2 + 1] - W[(128 + k0 + j) * 2 + 0];
        }

        const int n_pairs = (n_nodes + 1) >> 1;
        for (int p = gw; p < n_pairs; p += nwaves) {
            const int n = 2 * p + half;
            if (n < n_nodes) {
                const vfloat4 v = __builtin_nontemporal_load(
                    ((const vfloat4*)(Z + (size_t)n * 128)) + sub);

                float t0 = v.x * wds[0] + v.y * wds[1] + v.z * wds[2] + v.w * wds[3];
                float t1 = v.x * wdd[0] + v.y * wdd[1] + v.z * wdd[2] + v.w * wdd[3];

#pragma unroll
                for (int m = 16; m >= 1; m >>= 1) {   // within-half butterfly
                    t0 += __shfl_xor(t0, m, 64);
                    t1 += __shfl_xor(t1, m, 64);
                }
                if (sub == 0) {
                    dS[n] = t0;
                    dD[n] = t1;
                }
            }
        }
    }

    cg::grid_group grid = cg::this_grid();
    grid.sync();

    // ---- Phase B: gathers + softplus (edge data already in registers)
    float acc = 0.0f;
    if (full) {
        float d0 = dS[e01.x] + dD[e01.y];
        float d1 = dS[e01.z] + dD[e01.w];
        float d2 = dS[e23.x] + dD[e23.y];
        float d3 = dS[e23.z] + dD[e23.w];

        d0 = (yy.x != 0) ? -d0 : d0;
        d1 = (yy.y != 0) ? -d1 : d1;
        d2 = (yy.z != 0) ? -d2 : d2;
        d3 = (yy.w != 0) ? -d3 : d3;

        acc = (softplus(d0) + softplus(d1)) + (softplus(d2) + softplus(d3));
    } else if (base < n_edges) {
        for (int e = base; e < n_edges; ++e) {
            float d = dS[edges[2 * e]] + dD[edges[2 * e + 1]];
            d = (y[e] != 0) ? -d : d;
            acc += softplus(d);
        }
    }
    // overflow edges beyond the preloaded CAP (dead for n_edges <= CAP)
    for (int e = CAP + tid; e < n_edges; e += GRID * BLOCK) {
        float d = dS[edges[2 * e]] + dD[edges[2 * e + 1]];
        d = (y[e] != 0) ? -d : d;
        acc += softplus(d);
    }

    __shared__ float sm[BLOCK];
    sm[threadIdx.x] = acc;
    __syncthreads();
    for (int off = BLOCK / 2; off >= 1; off >>= 1) {
        if (threadIdx.x < off) sm[threadIdx.x] += sm[threadIdx.x + off];
        __syncthreads();
    }
    if (threadIdx.x == 0) partials[blockIdx.x] = sm[0];

    grid.sync();

    // ---- Final deterministic reduce on block 0
    if (blockIdx.x == 0) {
        float s = 0.0f;
        for (int i = threadIdx.x; i < GRID; i += BLOCK) s += partials[i];
        sm[threadIdx.x] = s;
        __syncthreads();
        for (int off = BLOCK / 2; off >= 1; off >>= 1) {
            if (threadIdx.x < off) sm[threadIdx.x] += sm[threadIdx.x + off];
            __syncthreads();
        }
        if (threadIdx.x == 0) out[0] = sm[0] * inv_m;
    }
}

extern "C" void kernel_launch(void* const* d_in, const int* in_sizes, int n_in,
                              void* d_out, int out_size, void* d_ws, size_t ws_size,
                              hipStream_t stream)
{
    const float* Z     = (const float*)d_in[0];
    const int*   edges = (const int*)  d_in[1];
    const int*   y     = (const int*)  d_in[2];
    const float* W     = (const float*)d_in[3];
    float* out = (float*)d_out;

    int n_nodes = in_sizes[0] / 128;
    int n_edges = in_sizes[1] / 2;
    float inv_m = 1.0f / (float)n_edges;

    // Workspace layout: dS | dD | partials
    char* ws = (char*)d_ws;
    float* dS = (float*)ws;        ws += (size_t)n_nodes * sizeof(float);
    float* dD = (float*)ws;        ws += (size_t)n_nodes * sizeof(float);
    float* partials = (float*)ws;

    void* args[] = { (void*)&Z, (void*)&W, (void*)&edges, (void*)&y,
                     (void*)&dS, (void*)&dD, (void*)&partials, (void*)&out,
                     (void*)&n_nodes, (void*)&n_edges, (void*)&inv_m };

    hipLaunchCooperativeKernel((const void*)fused_kernel,
                               dim3(GRID), dim3(BLOCK), args, 0, stream);
}

// Round 9
// 35.551 us; speedup vs baseline: 7.0459x; 7.0459x over previous
//
#include <hip/hip_runtime.h>
#include <hip/hip_bf16.h>

#define BLOCK 256
#define WAVES_PER_BLOCK (BLOCK / 64)
#define GRID_P 1024   // projection blocks (4096 waves) — proj is at HBM roofline
#define EPT    2      // edges per thread in edge_kernel (one vint4 = 2 edges)

typedef int   vint4 __attribute__((ext_vector_type(4)));
typedef int   vint2 __attribute__((ext_vector_type(2)));

// Phase 1: per-node logit-difference projections.
//   dS[n] = z_n . (W[0:128,1]   - W[0:128,0])     (node as src)
//   dD[n] = z_n . (W[128:256,1] - W[128:256,0])   (node as dst)
// (2-class identity: loss = softplus(s_wrong - s_correct), and
//  s1 - s0 = dS[src] + dD[dst].)
// Half-wave scheme: lanes 0..31 handle node 2p, lanes 32..63 node 2p+1.
// Lane reads float4 #sub of its row -> the wave reads 1024B fully contiguous.
// Butterfly (5 stages, 2 values) stays within each 32-lane half.
__global__ void __launch_bounds__(BLOCK) proj_kernel(
    const float* __restrict__ Z,
    const float* __restrict__ W,
    float*       __restrict__ dS,
    float*       __restrict__ dD,
    int n_nodes)
{
    const int lane = threadIdx.x & 63;
    const int wid  = threadIdx.x >> 6;
    const int sub  = lane & 31;   // float4 index within the 128-float row
    const int half = lane >> 5;   // which node of the pair
    const int gw   = blockIdx.x * WAVES_PER_BLOCK + wid;
    const int nwaves = gridDim.x * WAVES_PER_BLOCK;

    // This lane covers feature rows k0..k0+3; keep only the class-1 - class-0
    // weight differences.
    const int k0 = 4 * sub;
    float wds[4], wdd[4];
#pragma unroll
    for (int j = 0; j < 4; ++j) {
        wds[j] = W[(k0 + j) * 2 + 1]       - W[(k0 + j) * 2 + 0];
        wdd[j] = W[(128 + k0 + j) * 2 + 1] - W[(128 + k0 + j) * 2 + 0];
    }

    const int n_pairs = (n_nodes + 1) >> 1;
    for (int p = gw; p < n_pairs; p += nwaves) {
        const int n = 2 * p + half;
        if (n < n_nodes) {
            const float4 v = ((const float4*)(Z + (size_t)n * 128))[sub];

            float t0 = v.x * wds[0] + v.y * wds[1] + v.z * wds[2] + v.w * wds[3];
            float t1 = v.x * wdd[0] + v.y * wdd[1] + v.z * wdd[2] + v.w * wdd[3];

#pragma unroll
            for (int m = 16; m >= 1; m >>= 1) {   // within-half butterfly
                t0 += __shfl_xor(t0, m, 64);
                t1 += __shfl_xor(t1, m, 64);
            }
            if (sub == 0) {
                dS[n] = t0;
                dD[n] = t1;
            }
        }
    }
}

__device__ __forceinline__ float softplus(float x) {
    return fmaxf(x, 0.0f) + log1pf(expf(-fabsf(x)));
}

// Phase 2: per-edge loss. EPT=2: one vint4 load gives both edges' endpoints,
// one vint2 the labels -> 4 independent 4B gathers issue after a single
// stream-load wait. ~30 waves/CU resident (1954 blocks) for max latency
// hiding. Nontemporal streams keep the 800KB tables L2-resident.
__global__ void __launch_bounds__(BLOCK) edge_kernel(
    const float* __restrict__ dS,
    const float* __restrict__ dD,
    const int*   __restrict__ edges,
    const int*   __restrict__ y,
    float*       __restrict__ partials,
    int n_edges)
{
    const int tid  = blockIdx.x * BLOCK + threadIdx.x;
    const int base = tid * EPT;

    float acc = 0.0f;
    if (base + 1 < n_edges) {
        const vint4 e01 = __builtin_nontemporal_load(((const vint4*)edges) + tid);
        const vint2 yy  = __builtin_nontemporal_load(((const vint2*)y) + tid);

        float d0 = dS[e01.x] + dD[e01.y];
        float d1 = dS[e01.z] + dD[e01.w];

        d0 = (yy.x != 0) ? -d0 : d0;
        d1 = (yy.y != 0) ? -d1 : d1;

        acc = softplus(d0) + softplus(d1);
    } else if (base < n_edges) {
        for (int e = base; e < n_edges; ++e) {
            float d = dS[edges[2 * e]] + dD[edges[2 * e + 1]];
            d = (y[e] != 0) ? -d : d;
            acc += softplus(d);
        }
    }

    __shared__ float sm[BLOCK];
    sm[threadIdx.x] = acc;
    __syncthreads();
    for (int off = BLOCK / 2; off >= 1; off >>= 1) {
        if (threadIdx.x < off) sm[threadIdx.x] += sm[threadIdx.x + off];
        __syncthreads();
    }
    if (threadIdx.x == 0) partials[blockIdx.x] = sm[0];
}

// Phase 3: deterministic fixed-order final reduction.
__global__ void __launch_bounds__(BLOCK) reduce_kernel(
    const float* __restrict__ partials, int n,
    float* __restrict__ out, float inv_m)
{
    __shared__ float sm[BLOCK];
    float s = 0.0f;
    for (int i = threadIdx.x; i < n; i += BLOCK) s += partials[i];
    sm[threadIdx.x] = s;
    __syncthreads();
    for (int off = BLOCK / 2; off >= 1; off >>= 1) {
        if (threadIdx.x < off) sm[threadIdx.x] += sm[threadIdx.x + off];
        __syncthreads();
    }
    if (threadIdx.x == 0) out[0] = sm[0] * inv_m;
}

extern "C" void kernel_launch(void* const* d_in, const int* in_sizes, int n_in,
                              void* d_out, int out_size, void* d_ws, size_t ws_size,
                              hipStream_t stream)
{
    const float* Z     = (const float*)d_in[0];
    const int*   edges = (const int*)  d_in[1];
    const int*   y     = (const int*)  d_in[2];
    const float* W     = (const float*)d_in[3];
    float* out = (float*)d_out;

    const int n_nodes = in_sizes[0] / 128;
    const int n_edges = in_sizes[1] / 2;

    const int grid_e = (n_edges + EPT * BLOCK - 1) / (EPT * BLOCK);

    // Workspace layout: dS | dD | partials
    char* ws = (char*)d_ws;
    float* dS = (float*)ws;        ws += (size_t)n_nodes * sizeof(float);
    float* dD = (float*)ws;        ws += (size_t)n_nodes * sizeof(float);
    float* partials = (float*)ws;

    proj_kernel<<<GRID_P, BLOCK, 0, stream>>>(Z, W, dS, dD, n_nodes);
    edge_kernel<<<grid_e, BLOCK, 0, stream>>>(dS, dD, edges, y, partials, n_edges);
    reduce_kernel<<<1, BLOCK, 0, stream>>>(partials, grid_e, out,
                                           1.0f / (float)n_edges);
}

// Round 10
// 31.138 us; speedup vs baseline: 8.0445x; 1.1417x over previous
//
#include <hip/hip_runtime.h>
#include <hip/hip_bf16.h>

#define BLOCK 256
#define WAVES_PER_BLOCK (BLOCK / 64)
#define GRID_P 1024   // projection blocks (4096 waves) — proj is at HBM roofline
#define EPT    4      // edges per thread in edge_kernel

typedef int vint4 __attribute__((ext_vector_type(4)));

// Packed per-node table: hi 16 bits = bf16(dS[n]), lo 16 bits = bf16(dD[n]).
//   dS[n] = z_n . (W[0:128,1]   - W[0:128,0])     (node as src)
//   dD[n] = z_n . (W[128:256,1] - W[128:256,0])   (node as dst)
// 2-class identity: loss = softplus(s_wrong - s_correct), s1-s0 = dS[src]+dD[dst].
// One 400KB table doubles cacheline sharing between the two roles (src+dst
// accesses hit the same lines) -> higher L1 hit rate in the gather phase.

__device__ __forceinline__ float bf_hi(unsigned u) { return __uint_as_float(u & 0xFFFF0000u); }
__device__ __forceinline__ float bf_lo(unsigned u) { return __uint_as_float(u << 16); }

__device__ __forceinline__ unsigned pack_bf16(float hi, float lo) {
    unsigned h = (unsigned)__hip_bfloat16_raw(__float2bfloat16(hi)).x;
    unsigned l = (unsigned)__hip_bfloat16_raw(__float2bfloat16(lo)).x;
    return (h << 16) | l;
}

// Phase 1: per-node logit-difference projections -> packed table.
// Half-wave scheme: lanes 0..31 handle node 2p, lanes 32..63 node 2p+1.
// Lane reads float4 #sub of its row -> the wave reads 1024B fully contiguous.
// Butterfly (5 stages, 2 values) stays within each 32-lane half.
__global__ void __launch_bounds__(BLOCK) proj_kernel(
    const float* __restrict__ Z,
    const float* __restrict__ W,
    unsigned*    __restrict__ tbl,
    int n_nodes)
{
    const int lane = threadIdx.x & 63;
    const int wid  = threadIdx.x >> 6;
    const int sub  = lane & 31;   // float4 index within the 128-float row
    const int half = lane >> 5;   // which node of the pair
    const int gw   = blockIdx.x * WAVES_PER_BLOCK + wid;
    const int nwaves = gridDim.x * WAVES_PER_BLOCK;

    // This lane covers feature rows k0..k0+3; class-1 - class-0 differences.
    const int k0 = 4 * sub;
    float wds[4], wdd[4];
#pragma unroll
    for (int j = 0; j < 4; ++j) {
        wds[j] = W[(k0 + j) * 2 + 1]       - W[(k0 + j) * 2 + 0];
        wdd[j] = W[(128 + k0 + j) * 2 + 1] - W[(128 + k0 + j) * 2 + 0];
    }

    const int n_pairs = (n_nodes + 1) >> 1;
    for (int p = gw; p < n_pairs; p += nwaves) {
        const int n = 2 * p + half;
        if (n < n_nodes) {
            const float4 v = ((const float4*)(Z + (size_t)n * 128))[sub];

            float t0 = v.x * wds[0] + v.y * wds[1] + v.z * wds[2] + v.w * wds[3];
            float t1 = v.x * wdd[0] + v.y * wdd[1] + v.z * wdd[2] + v.w * wdd[3];

#pragma unroll
            for (int m = 16; m >= 1; m >>= 1) {   // within-half butterfly
                t0 += __shfl_xor(t0, m, 64);
                t1 += __shfl_xor(t1, m, 64);
            }
            if (sub == 0) tbl[n] = pack_bf16(t0, t1);   // hi=dS, lo=dD
        }
    }
}

__device__ __forceinline__ float softplus(float x) {
    return fmaxf(x, 0.0f) + log1pf(expf(-fabsf(x)));
}

// Phase 2: per-edge loss. EPT=4: 2x vint4 edge loads + 1x vint4 labels
// (nontemporal streams), 8 independent 4B gathers from the single 400KB
// L2-resident packed table, 4 softplus. One pass, no grid-stride.
__global__ void __launch_bounds__(BLOCK) edge_kernel(
    const unsigned* __restrict__ tbl,
    const int*      __restrict__ edges,
    const int*      __restrict__ y,
    float*          __restrict__ partials,
    int n_edges)
{
    const int tid  = blockIdx.x * BLOCK + threadIdx.x;
    const int base = tid * EPT;

    float acc = 0.0f;
    if (base + EPT - 1 < n_edges) {
        const vint4 e01 = __builtin_nontemporal_load(((const vint4*)edges) + 2 * tid);
        const vint4 e23 = __builtin_nontemporal_load(((const vint4*)edges) + 2 * tid + 1);
        const vint4 yy  = __builtin_nontemporal_load(((const vint4*)y) + tid);

        const unsigned s0 = tbl[e01.x], d0 = tbl[e01.y];
        const unsigned s1 = tbl[e01.z], d1 = tbl[e01.w];
        const unsigned s2 = tbl[e23.x], d2 = tbl[e23.y];
        const unsigned s3 = tbl[e23.z], d3 = tbl[e23.w];

        float v0 = bf_hi(s0) + bf_lo(d0);
        float v1 = bf_hi(s1) + bf_lo(d1);
        float v2 = bf_hi(s2) + bf_lo(d2);
        float v3 = bf_hi(s3) + bf_lo(d3);

        v0 = (yy.x != 0) ? -v0 : v0;
        v1 = (yy.y != 0) ? -v1 : v1;
        v2 = (yy.z != 0) ? -v2 : v2;
        v3 = (yy.w != 0) ? -v3 : v3;

        acc = (softplus(v0) + softplus(v1)) + (softplus(v2) + softplus(v3));
    } else if (base < n_edges) {
        for (int e = base; e < n_edges; ++e) {
            float d = bf_hi(tbl[edges[2 * e]]) + bf_lo(tbl[edges[2 * e + 1]]);
            d = (y[e] != 0) ? -d : d;
            acc += softplus(d);
        }
    }

    __shared__ float sm[BLOCK];
    sm[threadIdx.x] = acc;
    __syncthreads();
    for (int off = BLOCK / 2; off >= 1; off >>= 1) {
        if (threadIdx.x < off) sm[threadIdx.x] += sm[threadIdx.x + off];
        __syncthreads();
    }
    if (threadIdx.x == 0) partials[blockIdx.x] = sm[0];
}

// Phase 3: deterministic fixed-order final reduction.
__global__ void __launch_bounds__(BLOCK) reduce_kernel(
    const float* __restrict__ partials, int n,
    float* __restrict__ out, float inv_m)
{
    __shared__ float sm[BLOCK];
    float s = 0.0f;
    for (int i = threadIdx.x; i < n; i += BLOCK) s += partials[i];
    sm[threadIdx.x] = s;
    __syncthreads();
    for (int off = BLOCK / 2; off >= 1; off >>= 1) {
        if (threadIdx.x < off) sm[threadIdx.x] += sm[threadIdx.x + off];
        __syncthreads();
    }
    if (threadIdx.x == 0) out[0] = sm[0] * inv_m;
}

extern "C" void kernel_launch(void* const* d_in, const int* in_sizes, int n_in,
                              void* d_out, int out_size, void* d_ws, size_t ws_size,
                              hipStream_t stream)
{
    const float* Z     = (const float*)d_in[0];
    const int*   edges = (const int*)  d_in[1];
    const int*   y     = (const int*)  d_in[2];
    const float* W     = (const float*)d_in[3];
    float* out = (float*)d_out;

    const int n_nodes = in_sizes[0] / 128;
    const int n_edges = in_sizes[1] / 2;

    const int grid_e = (n_edges + EPT * BLOCK - 1) / (EPT * BLOCK);

    // Workspace layout: packed table | partials
    char* ws = (char*)d_ws;
    unsigned* tbl = (unsigned*)ws;   ws += (size_t)n_nodes * sizeof(unsigned);
    float* partials = (float*)ws;

    proj_kernel<<<GRID_P, BLOCK, 0, stream>>>(Z, W, tbl, n_nodes);
    edge_kernel<<<grid_e, BLOCK, 0, stream>>>(tbl, edges, y, partials, n_edges);
    reduce_kernel<<<1, BLOCK, 0, stream>>>(partials, grid_e, out,
                                           1.0f / (float)n_edges);
}